// Round 1
// baseline (1053.655 us; speedup 1.0000x reference)
//
#include <hip/hip_runtime.h>
#include <math.h>

#define SCALE 0.036084391824351613f  /* 1/sqrt(768) */

// ---------------- reduction helpers (blockDim must be multiple of 64) ----------------
__device__ __forceinline__ float blockReduceSum(float v, float* sh) {
#pragma unroll
  for (int o = 32; o > 0; o >>= 1) v += __shfl_xor(v, o, 64);
  int lane = threadIdx.x & 63, wid = threadIdx.x >> 6;
  __syncthreads();
  if (lane == 0) sh[wid] = v;
  __syncthreads();
  float r = sh[0];
  int nw = blockDim.x >> 6;
  for (int i = 1; i < nw; i++) r += sh[i];
  return r;
}

__device__ __forceinline__ float blockReduceMax(float v, float* sh) {
#pragma unroll
  for (int o = 32; o > 0; o >>= 1) v = fmaxf(v, __shfl_xor(v, o, 64));
  int lane = threadIdx.x & 63, wid = threadIdx.x >> 6;
  __syncthreads();
  if (lane == 0) sh[wid] = v;
  __syncthreads();
  float r = sh[0];
  int nw = blockDim.x >> 6;
  for (int i = 1; i < nw; i++) r = fmaxf(r, sh[i]);
  return r;
}

__device__ __forceinline__ float gelu_exact(float x) {
  return 0.5f * x * (1.0f + erff(x * 0.7071067811865476f));
}

// ---------------- K1: per-token LN+L2 stats -> A,B,C scalars ----------------
// logit[k,n] = A_n * dot(qg_k, x_n) - B_n * s1_k + C_n * qb_k
__global__ void __launch_bounds__(256) k_token_stats(
    const float* __restrict__ x, const float* __restrict__ g, const float* __restrict__ b,
    float* __restrict__ As, float* __restrict__ Bs, float* __restrict__ Cs) {
  __shared__ float sh[8];
  int n = blockIdx.x;
  const float* xr = x + (size_t)n * 768;
  int t = threadIdx.x;
  float x0 = xr[t], x1 = xr[t + 256], x2 = xr[t + 512];
  float sx  = blockReduceSum(x0 + x1 + x2, sh);
  float sxx = blockReduceSum(x0 * x0 + x1 * x1 + x2 * x2, sh);
  float mean = sx * (1.0f / 768.0f);
  float var = fmaxf(sxx * (1.0f / 768.0f) - mean * mean, 0.0f);
  float rs = rsqrtf(var + 1e-5f);
  float y0 = (x0 - mean) * rs * g[t] + b[t];
  float y1 = (x1 - mean) * rs * g[t + 256] + b[t + 256];
  float y2 = (x2 - mean) * rs * g[t + 512] + b[t + 512];
  float ss = blockReduceSum(y0 * y0 + y1 * y1 + y2 * y2, sh);
  if (t == 0) {
    float inv = 1.0f / fmaxf(sqrtf(ss), 1e-12f);
    float An = SCALE * inv * rs;
    As[n] = An;
    Bs[n] = An * mean;
    Cs[n] = SCALE * inv;
  }
}

// ---------------- K2: queries prep (LN + l2norm) + qg/s1/qb + bqn ----------------
__global__ void __launch_bounds__(256) k_prep_queries(
    const float* __restrict__ bq, const float* __restrict__ qn_g, const float* __restrict__ qn_b,
    const float* __restrict__ tn_g, const float* __restrict__ tn_b,
    float* __restrict__ qg, float* __restrict__ s1, float* __restrict__ qb,
    float* __restrict__ bqn) {
  __shared__ float sh[8];
  int k = blockIdx.x, t = threadIdx.x;
  const float* xr = bq + (size_t)k * 768;
  float x0 = xr[t], x1 = xr[t + 256], x2 = xr[t + 512];
  float sx  = blockReduceSum(x0 + x1 + x2, sh);
  float sxx = blockReduceSum(x0 * x0 + x1 * x1 + x2 * x2, sh);
  float mean = sx * (1.0f / 768.0f);
  float var = fmaxf(sxx * (1.0f / 768.0f) - mean * mean, 0.0f);
  float rs = rsqrtf(var + 1e-5f);
  float y0 = (x0 - mean) * rs * qn_g[t] + qn_b[t];
  float y1 = (x1 - mean) * rs * qn_g[t + 256] + qn_b[t + 256];
  float y2 = (x2 - mean) * rs * qn_g[t + 512] + qn_b[t + 512];
  float ss = blockReduceSum(y0 * y0 + y1 * y1 + y2 * y2, sh);
  float inv = 1.0f / fmaxf(sqrtf(ss), 1e-12f);
  float q0 = y0 * inv, q1 = y1 * inv, q2 = y2 * inv;
  float g0 = q0 * tn_g[t], g1 = q1 * tn_g[t + 256], g2 = q2 * tn_g[t + 512];
  qg[(size_t)k * 768 + t] = g0;
  qg[(size_t)k * 768 + t + 256] = g1;
  qg[(size_t)k * 768 + t + 512] = g2;
  float s1p = blockReduceSum(g0 + g1 + g2, sh);
  float qbp = blockReduceSum(q0 * tn_b[t] + q1 * tn_b[t + 256] + q2 * tn_b[t + 512], sh);
  if (t == 0) { s1[k] = s1p; qb[k] = qbp; }
  // bqn = l2norm(raw bq); sxx is already sum(x^2)
  float inv2 = 1.0f / fmaxf(sqrtf(sxx), 1e-12f);
  bqn[(size_t)k * 768 + t] = x0 * inv2;
  bqn[(size_t)k * 768 + t + 256] = x1 * inv2;
  bqn[(size_t)k * 768 + t + 512] = x2 * inv2;
}

// ---------------- K3: gram row-k squared error partials ----------------
__global__ void __launch_bounds__(256) k_gram(const float* __restrict__ bqn,
                                              float* __restrict__ gpart) {
  __shared__ float bk[768];
  __shared__ float arr[64];
  int k = blockIdx.x, t = threadIdx.x;
  bk[t] = bqn[(size_t)k * 768 + t];
  bk[t + 256] = bqn[(size_t)k * 768 + t + 256];
  bk[t + 512] = bqn[(size_t)k * 768 + t + 512];
  __syncthreads();
  int j = t >> 2, sub = t & 3;
  const float* bj = bqn + (size_t)j * 768 + sub * 192;
  float v = 0.0f;
  for (int d = 0; d < 192; d++) v += bk[sub * 192 + d] * bj[d];
  v += __shfl_xor(v, 1, 64);
  v += __shfl_xor(v, 2, 64);
  if (sub == 0) { float e = v - (j == k ? 1.0f : 0.0f); arr[j] = e * e; }
  __syncthreads();
  if (t < 64) {
    float s = arr[t];
#pragma unroll
    for (int o = 32; o > 0; o >>= 1) s += __shfl_xor(s, o, 64);
    if (t == 0) gpart[k] = s;
  }
}

// ---------------- K5: attn logits GEMM  L[b,k,n] ----------------
#define LPAD 68
__global__ void __launch_bounds__(256) k_attn_logits(
    const float* __restrict__ x, const float* __restrict__ qg,
    const float* __restrict__ s1, const float* __restrict__ qb,
    const float* __restrict__ As, const float* __restrict__ Bs, const float* __restrict__ Cs,
    float* __restrict__ L) {
  __shared__ __align__(16) float qgl[16][LPAD];  // [d][k]
  __shared__ __align__(16) float xl[16][LPAD];   // [d][n]
  int b = blockIdx.y, n0 = blockIdx.x * 64;
  int t = threadIdx.x, ty = t >> 4, tx = t & 15;
  int lr = t >> 2, lc = (t & 3) * 4;
  const float* xb = x + ((size_t)b * 4096 + n0) * 768;
  float acc[4][4] = {};
  for (int dk = 0; dk < 768; dk += 16) {
    float4 q4 = *(const float4*)(qg + (size_t)lr * 768 + dk + lc);
    float4 x4 = *(const float4*)(xb + (size_t)lr * 768 + dk + lc);
    __syncthreads();
    qgl[lc + 0][lr] = q4.x; qgl[lc + 1][lr] = q4.y; qgl[lc + 2][lr] = q4.z; qgl[lc + 3][lr] = q4.w;
    xl[lc + 0][lr] = x4.x;  xl[lc + 1][lr] = x4.y;  xl[lc + 2][lr] = x4.z;  xl[lc + 3][lr] = x4.w;
    __syncthreads();
#pragma unroll
    for (int d = 0; d < 16; d++) {
      float4 qv = *(const float4*)&qgl[d][ty * 4];
      float4 xv = *(const float4*)&xl[d][tx * 4];
      float qa[4] = {qv.x, qv.y, qv.z, qv.w};
      float xa[4] = {xv.x, xv.y, xv.z, xv.w};
#pragma unroll
      for (int i = 0; i < 4; i++)
#pragma unroll
        for (int jj = 0; jj < 4; jj++) acc[i][jj] = fmaf(qa[i], xa[jj], acc[i][jj]);
    }
  }
  size_t tokbase = (size_t)b * 4096 + n0 + tx * 4;
  float4 Av = *(const float4*)(As + tokbase);
  float4 Bv = *(const float4*)(Bs + tokbase);
  float4 Cv = *(const float4*)(Cs + tokbase);
#pragma unroll
  for (int i = 0; i < 4; i++) {
    float s1v = s1[ty * 4 + i], qbv = qb[ty * 4 + i];
    float4 o;
    o.x = Av.x * acc[i][0] - Bv.x * s1v + Cv.x * qbv;
    o.y = Av.y * acc[i][1] - Bv.y * s1v + Cv.y * qbv;
    o.z = Av.z * acc[i][2] - Bv.z * s1v + Cv.z * qbv;
    o.w = Av.w * acc[i][3] - Bv.w * s1v + Cv.w * qbv;
    *(float4*)(L + ((size_t)b * 64 + ty * 4 + i) * 4096 + n0 + tx * 4) = o;
  }
}

// ---------------- K6: softmax over n (row = b*64+k, width 4096) ----------------
__global__ void __launch_bounds__(256) k_softmax(float* __restrict__ L) {
  __shared__ float sh[8];
  size_t row = blockIdx.x;
  float* p = L + row * 4096;
  int t = threadIdx.x;
  float v[16];
  float mx = -INFINITY;
#pragma unroll
  for (int i = 0; i < 16; i++) { v[i] = p[t + i * 256]; mx = fmaxf(mx, v[i]); }
  mx = blockReduceMax(mx, sh);
  float s = 0.0f;
#pragma unroll
  for (int i = 0; i < 16; i++) { v[i] = expf(v[i] - mx); s += v[i]; }
  s = blockReduceSum(s, sh);
  float inv = 1.0f / s;
#pragma unroll
  for (int i = 0; i < 16; i++) p[t + i * 256] = v[i] * inv;
}

// ---------------- K7: basis_states GEMM  S[b,k,d] = sum_n W[b,k,n] x[b,n,d] ----------------
__global__ void __launch_bounds__(256) k_basis_states(
    const float* __restrict__ x, const float* __restrict__ W, float* __restrict__ S) {
  __shared__ __align__(16) float wl[16][LPAD];  // [n][k]
  __shared__ __align__(16) float xl[16][LPAD];  // [n][d]
  int b = blockIdx.y, d0 = blockIdx.x * 64;
  int t = threadIdx.x, ty = t >> 4, tx = t & 15;
  int kw = t >> 2, cw = (t & 3) * 4;   // W staging
  int nx = t >> 4, cx = (t & 15) * 4;  // x staging
  const float* Wb = W + (size_t)b * 64 * 4096;
  const float* xb = x + (size_t)b * 4096 * 768 + d0;
  float acc[4][4] = {};
  for (int n0 = 0; n0 < 4096; n0 += 16) {
    float4 w4 = *(const float4*)(Wb + (size_t)kw * 4096 + n0 + cw);
    float4 x4 = *(const float4*)(xb + (size_t)(n0 + nx) * 768 + cx);
    __syncthreads();
    wl[cw + 0][kw] = w4.x; wl[cw + 1][kw] = w4.y; wl[cw + 2][kw] = w4.z; wl[cw + 3][kw] = w4.w;
    *(float4*)&xl[nx][cx] = x4;
    __syncthreads();
#pragma unroll
    for (int n = 0; n < 16; n++) {
      float4 wv = *(const float4*)&wl[n][ty * 4];
      float4 xv = *(const float4*)&xl[n][tx * 4];
      float wa[4] = {wv.x, wv.y, wv.z, wv.w};
      float xa[4] = {xv.x, xv.y, xv.z, xv.w};
#pragma unroll
      for (int i = 0; i < 4; i++)
#pragma unroll
        for (int jj = 0; jj < 4; jj++) acc[i][jj] = fmaf(wa[i], xa[jj], acc[i][jj]);
    }
  }
#pragma unroll
  for (int i = 0; i < 4; i++) {
    float4 o = {acc[i][0], acc[i][1], acc[i][2], acc[i][3]};
    *(float4*)(S + ((size_t)b * 64 + ty * 4 + i) * 768 + d0 + tx * 4) = o;
  }
}

// ---------------- K8a: generic LN over 768-wide rows ----------------
__global__ void __launch_bounds__(256) k_ln768(
    const float* __restrict__ in, const float* __restrict__ g, const float* __restrict__ b,
    float* __restrict__ out) {
  __shared__ float sh[8];
  size_t row = blockIdx.x;
  const float* xr = in + row * 768;
  int t = threadIdx.x;
  float x0 = xr[t], x1 = xr[t + 256], x2 = xr[t + 512];
  float sx  = blockReduceSum(x0 + x1 + x2, sh);
  float sxx = blockReduceSum(x0 * x0 + x1 * x1 + x2 * x2, sh);
  float mean = sx * (1.0f / 768.0f);
  float var = fmaxf(sxx * (1.0f / 768.0f) - mean * mean, 0.0f);
  float rs = rsqrtf(var + 1e-5f);
  out[row * 768 + t]       = (x0 - mean) * rs * g[t] + b[t];
  out[row * 768 + t + 256] = (x1 - mean) * rs * g[t + 256] + b[t + 256];
  out[row * 768 + t + 512] = (x2 - mean) * rs * g[t + 512] + b[t + 512];
}

// ---------------- K8b: rh = gelu(r @ rw1 + rb1)  [2048x768]@[768x3072] ----------------
__global__ void __launch_bounds__(256) k_rh(
    const float* __restrict__ r, const float* __restrict__ w, const float* __restrict__ bias,
    float* __restrict__ rh) {
  __shared__ __align__(16) float al[16][LPAD];  // [d][m]
  __shared__ __align__(16) float bl[16][LPAD];  // [d][h]
  int h0 = blockIdx.x * 64, m0 = blockIdx.y * 64;
  int t = threadIdx.x, ty = t >> 4, tx = t & 15;
  int mr = t >> 2, mc = (t & 3) * 4;
  int dr = t >> 4, dc = (t & 15) * 4;
  float acc[4][4] = {};
  for (int dk = 0; dk < 768; dk += 16) {
    float4 a4 = *(const float4*)(r + (size_t)(m0 + mr) * 768 + dk + mc);
    float4 b4 = *(const float4*)(w + (size_t)(dk + dr) * 3072 + h0 + dc);
    __syncthreads();
    al[mc + 0][mr] = a4.x; al[mc + 1][mr] = a4.y; al[mc + 2][mr] = a4.z; al[mc + 3][mr] = a4.w;
    *(float4*)&bl[dr][dc] = b4;
    __syncthreads();
#pragma unroll
    for (int d = 0; d < 16; d++) {
      float4 av = *(const float4*)&al[d][ty * 4];
      float4 bv = *(const float4*)&bl[d][tx * 4];
      float aa[4] = {av.x, av.y, av.z, av.w};
      float ba[4] = {bv.x, bv.y, bv.z, bv.w};
#pragma unroll
      for (int i = 0; i < 4; i++)
#pragma unroll
        for (int jj = 0; jj < 4; jj++) acc[i][jj] = fmaf(aa[i], ba[jj], acc[i][jj]);
    }
  }
  float4 bb = *(const float4*)(bias + h0 + tx * 4);
  float ba[4] = {bb.x, bb.y, bb.z, bb.w};
#pragma unroll
  for (int i = 0; i < 4; i++) {
    float4 o;
    o.x = gelu_exact(acc[i][0] + ba[0]);
    o.y = gelu_exact(acc[i][1] + ba[1]);
    o.z = gelu_exact(acc[i][2] + ba[2]);
    o.w = gelu_exact(acc[i][3] + ba[3]);
    *(float4*)(rh + (size_t)(m0 + ty * 4 + i) * 3072 + h0 + tx * 4) = o;
  }
}

// ---------------- K9: routing scores = softplus(rh @ rw2 + rb2) ----------------
__global__ void __launch_bounds__(256) k_scores(
    const float* __restrict__ rh, const float* __restrict__ rw2, const float* __restrict__ rb2,
    float* __restrict__ scores) {
  __shared__ float sh[8];
  size_t row = blockIdx.x;
  const float* p = rh + row * 3072;
  int t = threadIdx.x;
  float s = 0.0f;
  for (int i = t; i < 3072; i += 256) s = fmaf(p[i], rw2[i], s);
  s = blockReduceSum(s, sh);
  if (t == 0) {
    float z = s + rb2[0];
    scores[row] = fmaxf(z, 0.0f) + log1pf(expf(-fabsf(z)));
  }
}

// ---------------- K10: top-8 per batch, renormalize ----------------
__global__ void __launch_bounds__(64) k_topk(
    const float* __restrict__ scores, float* __restrict__ rw_ws, float* __restrict__ rw_out) {
  int b = blockIdx.x, lane = threadIdx.x;
  float s = scores[b * 64 + lane];
  bool sel = false;
  for (int it = 0; it < 8; it++) {
    float v = sel ? -INFINITY : s;
    int idx = lane;
#pragma unroll
    for (int o = 32; o > 0; o >>= 1) {
      float v2 = __shfl_xor(v, o, 64);
      int i2 = __shfl_xor(idx, o, 64);
      if (v2 > v || (v2 == v && i2 < idx)) { v = v2; idx = i2; }
    }
    if (lane == idx) sel = true;
  }
  float w = sel ? s : 0.0f;
  float tot = w;
#pragma unroll
  for (int o = 32; o > 0; o >>= 1) tot += __shfl_xor(tot, o, 64);
  float wt = w / fmaxf(tot, 1e-8f);
  rw_ws[b * 64 + lane] = wt;
  rw_out[b * 64 + lane] = wt;
}

// ---------------- K11a: basis_summary (weighted sum) + both LNs -> fused [32,1536] ----------------
__global__ void __launch_bounds__(256) k_fused(
    const float* __restrict__ bs, const float* __restrict__ rw, const float* __restrict__ gf,
    const float* __restrict__ bn_g, const float* __restrict__ bn_b,
    const float* __restrict__ gn_g, const float* __restrict__ gn_b,
    float* __restrict__ fused) {
  __shared__ float sh[8];
  __shared__ float wsh[64];
  int b = blockIdx.x, t = threadIdx.x;
  if (t < 64) wsh[t] = rw[b * 64 + t];
  __syncthreads();
  float v0 = 0, v1 = 0, v2 = 0;
  const float* bsb = bs + (size_t)b * 64 * 768;
  for (int k = 0; k < 64; k++) {
    float w = wsh[k];
    if (w != 0.0f) {
      v0 = fmaf(w, bsb[(size_t)k * 768 + t], v0);
      v1 = fmaf(w, bsb[(size_t)k * 768 + t + 256], v1);
      v2 = fmaf(w, bsb[(size_t)k * 768 + t + 512], v2);
    }
  }
  // LN basis_summary -> fused[b, 768 + d]
  float sx  = blockReduceSum(v0 + v1 + v2, sh);
  float sxx = blockReduceSum(v0 * v0 + v1 * v1 + v2 * v2, sh);
  float mean = sx * (1.0f / 768.0f);
  float var = fmaxf(sxx * (1.0f / 768.0f) - mean * mean, 0.0f);
  float rs = rsqrtf(var + 1e-5f);
  float* fb = fused + (size_t)b * 1536;
  fb[768 + t]       = (v0 - mean) * rs * bn_g[t] + bn_b[t];
  fb[768 + t + 256] = (v1 - mean) * rs * bn_g[t + 256] + bn_b[t + 256];
  fb[768 + t + 512] = (v2 - mean) * rs * bn_g[t + 512] + bn_b[t + 512];
  // LN global -> fused[b, d]
  const float* gr = gf + (size_t)b * 768;
  float g0 = gr[t], g1 = gr[t + 256], g2 = gr[t + 512];
  float gsx  = blockReduceSum(g0 + g1 + g2, sh);
  float gsxx = blockReduceSum(g0 * g0 + g1 * g1 + g2 * g2, sh);
  float gm = gsx * (1.0f / 768.0f);
  float gv = fmaxf(gsxx * (1.0f / 768.0f) - gm * gm, 0.0f);
  float grs = rsqrtf(gv + 1e-5f);
  fb[t]       = (g0 - gm) * grs * gn_g[t] + gn_b[t];
  fb[t + 256] = (g1 - gm) * grs * gn_g[t + 256] + gn_b[t + 256];
  fb[t + 512] = (g2 - gm) * grs * gn_g[t + 512] + gn_b[t + 512];
}

// ---------------- K11b: h = gelu(fused @ hw1 + hb1)  [32,1536]@[1536,3072] ----------------
__global__ void __launch_bounds__(256) k_head1(
    const float* __restrict__ fused, const float* __restrict__ hw1, const float* __restrict__ hb1,
    float* __restrict__ h) {
  __shared__ float fl[1536];
  int b = blockIdx.y, h0 = blockIdx.x * 256, t = threadIdx.x;
  for (int i = t; i < 1536; i += 256) fl[i] = fused[(size_t)b * 1536 + i];
  __syncthreads();
  int hh = h0 + t;
  float acc = hb1[hh];
  for (int d = 0; d < 1536; d++) acc = fmaf(fl[d], hw1[(size_t)d * 3072 + hh], acc);
  h[(size_t)b * 3072 + hh] = gelu_exact(acc);
}

// ---------------- K11c: residual = h @ hw2 + hb2; final = base + residual ----------------
__global__ void __launch_bounds__(256) k_head2(
    const float* __restrict__ h, const float* __restrict__ hw2, const float* __restrict__ hb2,
    const float* __restrict__ base, float* __restrict__ out) {
  __shared__ float hl[3072];
  int b = blockIdx.y, c0 = blockIdx.x * 256, t = threadIdx.x;
  for (int i = t; i < 3072; i += 256) hl[i] = h[(size_t)b * 3072 + i];
  __syncthreads();
  int c = c0 + t;
  if (c < 1000) {
    float acc = hb2[c];
    for (int k = 0; k < 3072; k++) acc = fmaf(hl[k], hw2[(size_t)k * 1000 + c], acc);
    out[32000 + b * 1000 + c] = acc;
    out[b * 1000 + c] = base[b * 1000 + c] + acc;
  }
}

// ---------------- K12: sparse_loss + diversity_loss ----------------
__global__ void __launch_bounds__(256) k_losses(
    const float* __restrict__ scores, const float* __restrict__ gpart, float* __restrict__ out) {
  __shared__ float sh[8];
  int t = threadIdx.x;
  float s = 0.0f;
#pragma unroll
  for (int i = 0; i < 8; i++) s += scores[t + i * 256];
  s = blockReduceSum(s, sh);
  float gsum = (t < 64) ? gpart[t] : 0.0f;
  gsum = blockReduceSum(gsum, sh);
  if (t == 0) {
    out[66048] = s * (1.0f / 2048.0f);
    out[66049] = gsum * (1.0f / 4096.0f);
  }
}

// ---------------- launch ----------------
extern "C" void kernel_launch(void* const* d_in, const int* in_sizes, int n_in,
                              void* d_out, int out_size, void* d_ws, size_t ws_size,
                              hipStream_t stream) {
  const float* patch = (const float*)d_in[0];
  const float* gfeat = (const float*)d_in[1];
  const float* base  = (const float*)d_in[2];
  const float* bq    = (const float*)d_in[3];
  const float* qn_g  = (const float*)d_in[4];
  const float* qn_b  = (const float*)d_in[5];
  const float* tn_g  = (const float*)d_in[6];
  const float* tn_b  = (const float*)d_in[7];
  const float* bn_g  = (const float*)d_in[8];
  const float* bn_b  = (const float*)d_in[9];
  const float* gn_g  = (const float*)d_in[10];
  const float* gn_b  = (const float*)d_in[11];
  const float* rln_g = (const float*)d_in[12];
  const float* rln_b = (const float*)d_in[13];
  const float* rw1   = (const float*)d_in[14];
  const float* rb1   = (const float*)d_in[15];
  const float* rw2   = (const float*)d_in[16];
  const float* rb2   = (const float*)d_in[17];
  const float* hw1   = (const float*)d_in[18];
  const float* hb1   = (const float*)d_in[19];
  const float* hw2   = (const float*)d_in[20];
  const float* hb2   = (const float*)d_in[21];
  float* ws = (float*)d_ws;
  float* out = (float*)d_out;

  // workspace layout (floats)
  float* As     = ws + 0;
  float* Bs     = ws + 131072;
  float* Cs     = ws + 262144;
  float* qg     = ws + 393216;   // 64*768
  float* s1     = ws + 442368;   // 64
  float* qb     = ws + 442432;   // 64
  float* bqn    = ws + 442496;   // 64*768
  float* gpart  = ws + 491648;   // 64
  float* scores = ws + 491712;   // 2048
  float* rw_ws  = ws + 493760;   // 2048
  float* fused  = ws + 495808;   // 32*1536
  float* hbuf   = ws + 544960;   // 32*3072
  float* L      = ws + 643264;   // 32*64*4096
  float* bs     = ws + 9031872;  // 32*64*768
  float* r      = ws + 10604736; // 32*64*768
  float* rh     = ws + 12177600; // 2048*3072  (end 18469056 floats = 73.9 MB)

  k_token_stats<<<dim3(131072), 256, 0, stream>>>(patch, tn_g, tn_b, As, Bs, Cs);
  k_prep_queries<<<dim3(64), 256, 0, stream>>>(bq, qn_g, qn_b, tn_g, tn_b, qg, s1, qb, bqn);
  k_gram<<<dim3(64), 256, 0, stream>>>(bqn, gpart);
  k_attn_logits<<<dim3(64, 32), 256, 0, stream>>>(patch, qg, s1, qb, As, Bs, Cs, L);
  k_softmax<<<dim3(2048), 256, 0, stream>>>(L);
  k_basis_states<<<dim3(12, 32), 256, 0, stream>>>(patch, L, bs);
  k_ln768<<<dim3(2048), 256, 0, stream>>>(bs, rln_g, rln_b, r);
  k_rh<<<dim3(48, 32), 256, 0, stream>>>(r, rw1, rb1, rh);
  k_scores<<<dim3(2048), 256, 0, stream>>>(rh, rw2, rb2, scores);
  k_topk<<<dim3(32), 64, 0, stream>>>(scores, rw_ws, out + 64000);
  k_fused<<<dim3(32), 256, 0, stream>>>(bs, rw_ws, gfeat, bn_g, bn_b, gn_g, gn_b, fused);
  k_head1<<<dim3(12, 32), 256, 0, stream>>>(fused, hw1, hb1, hbuf);
  k_head2<<<dim3(4, 32), 256, 0, stream>>>(hbuf, hw2, hb2, base, out);
  k_losses<<<dim3(1), 256, 0, stream>>>(scores, gpart, out);
}

// Round 4
// 690.647 us; speedup vs baseline: 1.5256x; 1.5256x over previous
//
#include <hip/hip_runtime.h>
#include <math.h>

#define SCALE 0.036084391824351613f /* 1/sqrt(768) */

typedef unsigned short us;
typedef __attribute__((ext_vector_type(8))) short short8;
typedef __attribute__((ext_vector_type(4))) float f32x4;
#define MFMA16(a, b, c) __builtin_amdgcn_mfma_f32_16x16x32_bf16(a, b, c, 0, 0, 0)

__device__ __forceinline__ us f2bf(float f) {
  unsigned u = __float_as_uint(f);
  unsigned r = (u + 0x7fffu + ((u >> 16) & 1u)) >> 16;
  return (us)r;
}
__device__ __forceinline__ float bf2f(us u) { return __uint_as_float(((unsigned)u) << 16); }

// split 8 f32 into hi/lo bf16 (hi = rn(x), lo = rn(x - hi))
__device__ __forceinline__ void split8(f32x4 a, f32x4 b, short8& hi, short8& lo) {
  float x[8] = {a[0], a[1], a[2], a[3], b[0], b[1], b[2], b[3]};
#pragma unroll
  for (int i = 0; i < 8; i++) {
    us h = f2bf(x[i]);
    hi[i] = (short)h;
    lo[i] = (short)f2bf(x[i] - bf2f(h));
  }
}

// ---------------- reduction helpers (blockDim = 256) ----------------
__device__ __forceinline__ float blockReduceSum(float v, float* sh) {
#pragma unroll
  for (int o = 32; o > 0; o >>= 1) v += __shfl_xor(v, o, 64);
  int lane = threadIdx.x & 63, wid = threadIdx.x >> 6;
  __syncthreads();
  if (lane == 0) sh[wid] = v;
  __syncthreads();
  float r = sh[0];
  int nw = blockDim.x >> 6;
  for (int i = 1; i < nw; i++) r += sh[i];
  return r;
}

__device__ __forceinline__ float blockReduceMax(float v, float* sh) {
#pragma unroll
  for (int o = 32; o > 0; o >>= 1) v = fmaxf(v, __shfl_xor(v, o, 64));
  int lane = threadIdx.x & 63, wid = threadIdx.x >> 6;
  __syncthreads();
  if (lane == 0) sh[wid] = v;
  __syncthreads();
  float r = sh[0];
  int nw = blockDim.x >> 6;
  for (int i = 1; i < nw; i++) r = fmaxf(r, sh[i]);
  return r;
}

__device__ __forceinline__ float gelu_exact(float x) {
  return 0.5f * x * (1.0f + erff(x * 0.7071067811865476f));
}

// ---------------- K1: per-token LN+L2 stats -> A,B,C scalars ----------------
__global__ void __launch_bounds__(256) k_token_stats(
    const float* __restrict__ x, const float* __restrict__ g, const float* __restrict__ b,
    float* __restrict__ As, float* __restrict__ Bs, float* __restrict__ Cs) {
  __shared__ float sh[8];
  int n = blockIdx.x;
  const float* xr = x + (size_t)n * 768;
  int t = threadIdx.x;
  float x0 = xr[t], x1 = xr[t + 256], x2 = xr[t + 512];
  float sx = blockReduceSum(x0 + x1 + x2, sh);
  float sxx = blockReduceSum(x0 * x0 + x1 * x1 + x2 * x2, sh);
  float mean = sx * (1.0f / 768.0f);
  float var = fmaxf(sxx * (1.0f / 768.0f) - mean * mean, 0.0f);
  float rs = rsqrtf(var + 1e-5f);
  float y0 = (x0 - mean) * rs * g[t] + b[t];
  float y1 = (x1 - mean) * rs * g[t + 256] + b[t + 256];
  float y2 = (x2 - mean) * rs * g[t + 512] + b[t + 512];
  float ss = blockReduceSum(y0 * y0 + y1 * y1 + y2 * y2, sh);
  if (t == 0) {
    float inv = 1.0f / fmaxf(sqrtf(ss), 1e-12f);
    float An = SCALE * inv * rs;
    As[n] = An;
    Bs[n] = An * mean;
    Cs[n] = SCALE * inv;
  }
}

// ---------------- K2: queries prep -> qg (f32), s1, qb, bqn ----------------
__global__ void __launch_bounds__(256) k_prep_queries(
    const float* __restrict__ bq, const float* __restrict__ qn_g, const float* __restrict__ qn_b,
    const float* __restrict__ tn_g, const float* __restrict__ tn_b,
    float* __restrict__ qg, float* __restrict__ s1, float* __restrict__ qb,
    float* __restrict__ bqn) {
  __shared__ float sh[8];
  int k = blockIdx.x, t = threadIdx.x;
  const float* xr = bq + (size_t)k * 768;
  float x0 = xr[t], x1 = xr[t + 256], x2 = xr[t + 512];
  float sx = blockReduceSum(x0 + x1 + x2, sh);
  float sxx = blockReduceSum(x0 * x0 + x1 * x1 + x2 * x2, sh);
  float mean = sx * (1.0f / 768.0f);
  float var = fmaxf(sxx * (1.0f / 768.0f) - mean * mean, 0.0f);
  float rs = rsqrtf(var + 1e-5f);
  float y0 = (x0 - mean) * rs * qn_g[t] + qn_b[t];
  float y1 = (x1 - mean) * rs * qn_g[t + 256] + qn_b[t + 256];
  float y2 = (x2 - mean) * rs * qn_g[t + 512] + qn_b[t + 512];
  float ss = blockReduceSum(y0 * y0 + y1 * y1 + y2 * y2, sh);
  float inv = 1.0f / fmaxf(sqrtf(ss), 1e-12f);
  float q0 = y0 * inv, q1 = y1 * inv, q2 = y2 * inv;
  float g0 = q0 * tn_g[t], g1 = q1 * tn_g[t + 256], g2 = q2 * tn_g[t + 512];
  qg[(size_t)k * 768 + t] = g0;
  qg[(size_t)k * 768 + t + 256] = g1;
  qg[(size_t)k * 768 + t + 512] = g2;
  float s1p = blockReduceSum(g0 + g1 + g2, sh);
  float qbp = blockReduceSum(q0 * tn_b[t] + q1 * tn_b[t + 256] + q2 * tn_b[t + 512], sh);
  if (t == 0) { s1[k] = s1p; qb[k] = qbp; }
  float inv2 = 1.0f / fmaxf(sqrtf(sxx), 1e-12f);
  bqn[(size_t)k * 768 + t] = x0 * inv2;
  bqn[(size_t)k * 768 + t + 256] = x1 * inv2;
  bqn[(size_t)k * 768 + t + 512] = x2 * inv2;
}

// ---------------- K3: gram row-k squared error partials ----------------
__global__ void __launch_bounds__(256) k_gram(const float* __restrict__ bqn,
                                              float* __restrict__ gpart) {
  __shared__ float bk[768];
  __shared__ float arr[64];
  int k = blockIdx.x, t = threadIdx.x;
  bk[t] = bqn[(size_t)k * 768 + t];
  bk[t + 256] = bqn[(size_t)k * 768 + t + 256];
  bk[t + 512] = bqn[(size_t)k * 768 + t + 512];
  __syncthreads();
  int j = t >> 2, sub = t & 3;
  const float* bj = bqn + (size_t)j * 768 + sub * 192;
  float v = 0.0f;
  for (int d = 0; d < 192; d++) v += bk[sub * 192 + d] * bj[d];
  v += __shfl_xor(v, 1, 64);
  v += __shfl_xor(v, 2, 64);
  if (sub == 0) { float e = v - (j == k ? 1.0f : 0.0f); arr[j] = e * e; }
  __syncthreads();
  if (t < 64) {
    float s = arr[t];
#pragma unroll
    for (int o = 32; o > 0; o >>= 1) s += __shfl_xor(s, o, 64);
    if (t == 0) gpart[k] = s;
  }
}

// ---------------- K4: transpose rw1 [768,3072] -> w1T [3072,768] f32 ----------------
__global__ void __launch_bounds__(256) k_w1t(const float* __restrict__ rw1,
                                             float* __restrict__ w1T) {
  __shared__ float tl[32][33];
  int d0 = blockIdx.x * 32, h0 = blockIdx.y * 32;
  int t = threadIdx.x, tx = t & 31, ty = t >> 5;
#pragma unroll
  for (int j = 0; j < 4; j++)
    tl[ty + j * 8][tx] = rw1[(size_t)(d0 + ty + j * 8) * 3072 + h0 + tx];
  __syncthreads();
#pragma unroll
  for (int j = 0; j < 4; j++)
    w1T[(size_t)(h0 + ty + j * 8) * 768 + d0 + tx] = tl[tx][ty + j * 8];
}

// ---------------- K5: attn logits GEMM (split-bf16 MFMA, 4-term)  L[b,k,n] -------
// block: 64k x 128n, 4 waves; hi/lo split => 4 MFMA per fragment pair (f32-grade).
__global__ void __launch_bounds__(256) k_attn_mfma(
    const float* __restrict__ x, const float* __restrict__ qg,
    const float* __restrict__ s1v, const float* __restrict__ qbv,
    const float* __restrict__ As, const float* __restrict__ Bs, const float* __restrict__ Cs,
    float* __restrict__ L) {
  __shared__ __align__(16) us qsh[64 * 32], qsl[64 * 32];
  __shared__ __align__(16) us xsh[128 * 32], xsl[128 * 32];
  const int b = blockIdx.y, n0 = blockIdx.x * 128;
  const int t = threadIdx.x, w = t >> 6, l = t & 63;
  const int sr = t >> 2, sq = t & 3;
  const float* qsrc = qg + (size_t)sr * 768 + sq * 8;
  const float* xsrc = x + ((size_t)b * 4096 + n0 + sr) * 768 + sq * 8;
  f32x4 acc[4][2];
#pragma unroll
  for (int i = 0; i < 4; i++)
#pragma unroll
    for (int j = 0; j < 2; j++) acc[i][j] = (f32x4){0.f, 0.f, 0.f, 0.f};
  f32x4 q0a = *(const f32x4*)qsrc, q0b = *(const f32x4*)(qsrc + 4);
  f32x4 x0a = *(const f32x4*)xsrc, x0b = *(const f32x4*)(xsrc + 4);
  f32x4 x1a = *(const f32x4*)(xsrc + (size_t)64 * 768);
  f32x4 x1b = *(const f32x4*)(xsrc + (size_t)64 * 768 + 4);
  for (int dk = 0; dk < 768; dk += 32) {
    short8 hi, lo;
    __syncthreads();
    split8(q0a, q0b, hi, lo);
    *(short8*)&qsh[sr * 32 + sq * 8] = hi; *(short8*)&qsl[sr * 32 + sq * 8] = lo;
    split8(x0a, x0b, hi, lo);
    *(short8*)&xsh[sr * 32 + sq * 8] = hi; *(short8*)&xsl[sr * 32 + sq * 8] = lo;
    split8(x1a, x1b, hi, lo);
    *(short8*)&xsh[(sr + 64) * 32 + sq * 8] = hi; *(short8*)&xsl[(sr + 64) * 32 + sq * 8] = lo;
    __syncthreads();
    if (dk + 32 < 768) {
      int d2 = dk + 32;
      q0a = *(const f32x4*)(qsrc + d2); q0b = *(const f32x4*)(qsrc + d2 + 4);
      x0a = *(const f32x4*)(xsrc + d2); x0b = *(const f32x4*)(xsrc + d2 + 4);
      x1a = *(const f32x4*)(xsrc + (size_t)64 * 768 + d2);
      x1b = *(const f32x4*)(xsrc + (size_t)64 * 768 + d2 + 4);
    }
    short8 ah[4], al[4];
#pragma unroll
    for (int kt = 0; kt < 4; kt++) {
      int off = (kt * 16 + (l & 15)) * 32 + (l >> 4) * 8;
      ah[kt] = *(const short8*)&qsh[off];
      al[kt] = *(const short8*)&qsl[off];
    }
#pragma unroll
    for (int nt = 0; nt < 2; nt++) {
      int off = (w * 32 + nt * 16 + (l & 15)) * 32 + (l >> 4) * 8;
      short8 bh = *(const short8*)&xsh[off];
      short8 bl = *(const short8*)&xsl[off];
#pragma unroll
      for (int kt = 0; kt < 4; kt++) {
        acc[kt][nt] = MFMA16(ah[kt], bh, acc[kt][nt]);
        acc[kt][nt] = MFMA16(ah[kt], bl, acc[kt][nt]);
        acc[kt][nt] = MFMA16(al[kt], bh, acc[kt][nt]);
        acc[kt][nt] = MFMA16(al[kt], bl, acc[kt][nt]);
      }
    }
  }
#pragma unroll
  for (int nt = 0; nt < 2; nt++) {
    int n = n0 + w * 32 + nt * 16 + (l & 15);
    size_t gn = (size_t)b * 4096 + n;
    float Av = As[gn], Bv = Bs[gn], Cv = Cs[gn];
#pragma unroll
    for (int kt = 0; kt < 4; kt++) {
#pragma unroll
      for (int r = 0; r < 4; r++) {
        int k = kt * 16 + (l >> 4) * 4 + r;
        L[((size_t)b * 64 + k) * 4096 + n] = Av * acc[kt][nt][r] - Bv * s1v[k] + Cv * qbv[k];
      }
    }
  }
}

// ---------------- K6: softmax over n (f32 in-place) ----------------
__global__ void __launch_bounds__(256) k_softmax(float* __restrict__ L) {
  __shared__ float sh[8];
  size_t row = blockIdx.x;
  float* p = L + row * 4096;
  int t = threadIdx.x;
  float v[16];
  float mx = -INFINITY;
#pragma unroll
  for (int i = 0; i < 16; i++) { v[i] = p[t + i * 256]; mx = fmaxf(mx, v[i]); }
  mx = blockReduceMax(mx, sh);
  float s = 0.0f;
#pragma unroll
  for (int i = 0; i < 16; i++) { v[i] = expf(v[i] - mx); s += v[i]; }
  s = blockReduceSum(s, sh);
  float inv = 1.0f / s;
#pragma unroll
  for (int i = 0; i < 16; i++) p[t + i * 256] = v[i] * inv;
}

// ---------------- K7: zero bs ----------------
__global__ void __launch_bounds__(256) k_zero(float* __restrict__ p) {
  ((f32x4*)p)[blockIdx.x * 256 + threadIdx.x] = (f32x4){0.f, 0.f, 0.f, 0.f};
}

// ---------------- K8: basis_states GEMM (split-bf16 MFMA 4-term, contraction over n)
// S[b,k,d] += sum_n W[b,k,n] x[b,n,d].  block: 64k x 128d, n-chunk 1024 (z).
__global__ void __launch_bounds__(256) k_pv_mfma(
    const float* __restrict__ x, const float* __restrict__ W, float* __restrict__ S) {
  __shared__ __align__(16) us wth[64 * 32], wtl[64 * 32];
  __shared__ __align__(16) us xth[8 * 32 * 16], xtl[8 * 32 * 16];
  const int b = blockIdx.y, d0 = blockIdx.x * 128, nb = blockIdx.z * 1024;
  const int t = threadIdx.x, w = t >> 6, l = t & 63;
  const float* wsrc = W + ((size_t)b * 64 + (t >> 2)) * 4096 + nb + (t & 3) * 8;
  const int gg = t >> 6, nn = (t >> 1) & 31, hh = t & 1;
  const float* xsrc0 = x + ((size_t)b * 4096 + nb + nn) * 768 + d0 + gg * 16 + hh * 8;
  const float* xsrc1 = xsrc0 + 64;  // groups 4..7
  f32x4 acc[4][2];
#pragma unroll
  for (int i = 0; i < 4; i++)
#pragma unroll
    for (int j = 0; j < 2; j++) acc[i][j] = (f32x4){0.f, 0.f, 0.f, 0.f};
  f32x4 w0a = *(const f32x4*)wsrc, w0b = *(const f32x4*)(wsrc + 4);
  f32x4 xa0 = *(const f32x4*)xsrc0, xb0 = *(const f32x4*)(xsrc0 + 4);
  f32x4 xa1 = *(const f32x4*)xsrc1, xb1 = *(const f32x4*)(xsrc1 + 4);
  for (int ns = 0; ns < 1024; ns += 32) {
    short8 hi, lo;
    __syncthreads();
    split8(w0a, w0b, hi, lo);
    *(short8*)&wth[(t >> 2) * 32 + (t & 3) * 8] = hi;
    *(short8*)&wtl[(t >> 2) * 32 + (t & 3) * 8] = lo;
    split8(xa0, xb0, hi, lo);
    *(short8*)&xth[(size_t)t * 8] = hi; *(short8*)&xtl[(size_t)t * 8] = lo;
    split8(xa1, xb1, hi, lo);
    *(short8*)&xth[((size_t)t + 256) * 8] = hi; *(short8*)&xtl[((size_t)t + 256) * 8] = lo;
    __syncthreads();
    if (ns + 32 < 1024) {
      w0a = *(const f32x4*)(wsrc + ns + 32); w0b = *(const f32x4*)(wsrc + ns + 36);
      const float* p0 = xsrc0 + (size_t)(ns + 32) * 768;
      xa0 = *(const f32x4*)p0; xb0 = *(const f32x4*)(p0 + 4);
      xa1 = *(const f32x4*)(p0 + 64); xb1 = *(const f32x4*)(p0 + 68);
    }
    short8 ah[4], al[4];
#pragma unroll
    for (int kt = 0; kt < 4; kt++) {
      int off = (kt * 16 + (l & 15)) * 32 + (l >> 4) * 8;
      ah[kt] = *(const short8*)&wth[off];
      al[kt] = *(const short8*)&wtl[off];
    }
#pragma unroll
    for (int dt = 0; dt < 2; dt++) {
      const us* gph = &xth[(2 * w + dt) * 512];
      const us* gpl = &xtl[(2 * w + dt) * 512];
      int rb = (l >> 4) * 8, cc = l & 15;
      short8 bh, bl;
#pragma unroll
      for (int i = 0; i < 8; i++) {
        bh[i] = (short)gph[(rb + i) * 16 + cc];
        bl[i] = (short)gpl[(rb + i) * 16 + cc];
      }
#pragma unroll
      for (int kt = 0; kt < 4; kt++) {
        acc[kt][dt] = MFMA16(ah[kt], bh, acc[kt][dt]);
        acc[kt][dt] = MFMA16(ah[kt], bl, acc[kt][dt]);
        acc[kt][dt] = MFMA16(al[kt], bh, acc[kt][dt]);
        acc[kt][dt] = MFMA16(al[kt], bl, acc[kt][dt]);
      }
    }
  }
#pragma unroll
  for (int dt = 0; dt < 2; dt++) {
    int d = d0 + w * 32 + dt * 16 + (l & 15);
#pragma unroll
    for (int kt = 0; kt < 4; kt++) {
#pragma unroll
      for (int r = 0; r < 4; r++) {
        int k = kt * 16 + (l >> 4) * 4 + r;
        atomicAdd(&S[((size_t)b * 64 + k) * 768 + d], acc[kt][dt][r]);
      }
    }
  }
}

// ---------------- K9: LN over 768 rows -> f32 out ----------------
__global__ void __launch_bounds__(256) k_ln768(
    const float* __restrict__ in, const float* __restrict__ g, const float* __restrict__ b,
    float* __restrict__ out) {
  __shared__ float sh[8];
  size_t row = blockIdx.x;
  const float* xr = in + row * 768;
  int t = threadIdx.x;
  float x0 = xr[t], x1 = xr[t + 256], x2 = xr[t + 512];
  float sx = blockReduceSum(x0 + x1 + x2, sh);
  float sxx = blockReduceSum(x0 * x0 + x1 * x1 + x2 * x2, sh);
  float mean = sx * (1.0f / 768.0f);
  float var = fmaxf(sxx * (1.0f / 768.0f) - mean * mean, 0.0f);
  float rs = rsqrtf(var + 1e-5f);
  out[row * 768 + t] = (x0 - mean) * rs * g[t] + b[t];
  out[row * 768 + t + 256] = (x1 - mean) * rs * g[t + 256] + b[t + 256];
  out[row * 768 + t + 512] = (x2 - mean) * rs * g[t + 512] + b[t + 512];
}

// ---------------- K10: rh = gelu(r @ rw1 + rb1) (split-bf16 MFMA 4-term) -> f32 --
// block: 64m x 128h; A = r [2048,768] f32, B = w1T [3072,768] f32 (K-contig).
__global__ void __launch_bounds__(256) k_rh_mfma(
    const float* __restrict__ r, const float* __restrict__ w1T, const float* __restrict__ rb1,
    float* __restrict__ rh) {
  __shared__ __align__(16) us ash[64 * 32], asl[64 * 32];
  __shared__ __align__(16) us bsh[128 * 32], bsl[128 * 32];
  const int h0 = blockIdx.x * 128, m0 = blockIdx.y * 64;
  const int t = threadIdx.x, w = t >> 6, l = t & 63;
  const int sr = t >> 2, sq = t & 3;
  const float* asrc = r + (size_t)(m0 + sr) * 768 + sq * 8;
  const float* bsrc = w1T + (size_t)(h0 + sr) * 768 + sq * 8;
  f32x4 acc[4][2];
#pragma unroll
  for (int i = 0; i < 4; i++)
#pragma unroll
    for (int j = 0; j < 2; j++) acc[i][j] = (f32x4){0.f, 0.f, 0.f, 0.f};
  f32x4 a0a = *(const f32x4*)asrc, a0b = *(const f32x4*)(asrc + 4);
  f32x4 b0a = *(const f32x4*)bsrc, b0b = *(const f32x4*)(bsrc + 4);
  f32x4 b1a = *(const f32x4*)(bsrc + (size_t)64 * 768);
  f32x4 b1b = *(const f32x4*)(bsrc + (size_t)64 * 768 + 4);
  for (int dk = 0; dk < 768; dk += 32) {
    short8 hi, lo;
    __syncthreads();
    split8(a0a, a0b, hi, lo);
    *(short8*)&ash[sr * 32 + sq * 8] = hi; *(short8*)&asl[sr * 32 + sq * 8] = lo;
    split8(b0a, b0b, hi, lo);
    *(short8*)&bsh[sr * 32 + sq * 8] = hi; *(short8*)&bsl[sr * 32 + sq * 8] = lo;
    split8(b1a, b1b, hi, lo);
    *(short8*)&bsh[(sr + 64) * 32 + sq * 8] = hi; *(short8*)&bsl[(sr + 64) * 32 + sq * 8] = lo;
    __syncthreads();
    if (dk + 32 < 768) {
      int d2 = dk + 32;
      a0a = *(const f32x4*)(asrc + d2); a0b = *(const f32x4*)(asrc + d2 + 4);
      b0a = *(const f32x4*)(bsrc + d2); b0b = *(const f32x4*)(bsrc + d2 + 4);
      b1a = *(const f32x4*)(bsrc + (size_t)64 * 768 + d2);
      b1b = *(const f32x4*)(bsrc + (size_t)64 * 768 + d2 + 4);
    }
    short8 ah[4], al[4];
#pragma unroll
    for (int kt = 0; kt < 4; kt++) {
      int off = (kt * 16 + (l & 15)) * 32 + (l >> 4) * 8;
      ah[kt] = *(const short8*)&ash[off];
      al[kt] = *(const short8*)&asl[off];
    }
#pragma unroll
    for (int nt = 0; nt < 2; nt++) {
      int off = (w * 32 + nt * 16 + (l & 15)) * 32 + (l >> 4) * 8;
      short8 bh = *(const short8*)&bsh[off];
      short8 bl = *(const short8*)&bsl[off];
#pragma unroll
      for (int kt = 0; kt < 4; kt++) {
        acc[kt][nt] = MFMA16(ah[kt], bh, acc[kt][nt]);
        acc[kt][nt] = MFMA16(ah[kt], bl, acc[kt][nt]);
        acc[kt][nt] = MFMA16(al[kt], bh, acc[kt][nt]);
        acc[kt][nt] = MFMA16(al[kt], bl, acc[kt][nt]);
      }
    }
  }
#pragma unroll
  for (int nt = 0; nt < 2; nt++) {
    int h = h0 + w * 32 + nt * 16 + (l & 15);
    float bias = rb1[h];
#pragma unroll
    for (int kt = 0; kt < 4; kt++) {
#pragma unroll
      for (int r2 = 0; r2 < 4; r2++) {
        int m = m0 + kt * 16 + (l >> 4) * 4 + r2;
        rh[(size_t)m * 3072 + h] = gelu_exact(acc[kt][nt][r2] + bias);
      }
    }
  }
}

// ---------------- K11: routing scores = softplus(rh . rw2 + rb2) ----------------
__global__ void __launch_bounds__(256) k_scores(
    const float* __restrict__ rh, const float* __restrict__ rw2, const float* __restrict__ rb2,
    float* __restrict__ scores) {
  __shared__ float sh[8];
  size_t row = blockIdx.x;
  const float* p = rh + row * 3072;
  int t = threadIdx.x;
  float s = 0.0f;
  for (int i = t; i < 3072; i += 256) s = fmaf(p[i], rw2[i], s);
  s = blockReduceSum(s, sh);
  if (t == 0) {
    float z = s + rb2[0];
    scores[row] = fmaxf(z, 0.0f) + log1pf(expf(-fabsf(z)));
  }
}

// ---------------- K12: top-8 per batch, renormalize ----------------
__global__ void __launch_bounds__(64) k_topk(
    const float* __restrict__ scores, float* __restrict__ rw_ws, float* __restrict__ rw_out) {
  int b = blockIdx.x, lane = threadIdx.x;
  float s = scores[b * 64 + lane];
  bool sel = false;
  for (int it = 0; it < 8; it++) {
    float v = sel ? -INFINITY : s;
    int idx = lane;
#pragma unroll
    for (int o = 32; o > 0; o >>= 1) {
      float v2 = __shfl_xor(v, o, 64);
      int i2 = __shfl_xor(idx, o, 64);
      if (v2 > v || (v2 == v && i2 < idx)) { v = v2; idx = i2; }
    }
    if (lane == idx) sel = true;
  }
  float w = sel ? s : 0.0f;
  float tot = w;
#pragma unroll
  for (int o = 32; o > 0; o >>= 1) tot += __shfl_xor(tot, o, 64);
  float wt = w / fmaxf(tot, 1e-8f);
  rw_ws[b * 64 + lane] = wt;
  rw_out[b * 64 + lane] = wt;
}

// ---------------- K13: basis_summary + both LNs -> fused [32,1536] ----------------
__global__ void __launch_bounds__(256) k_fused(
    const float* __restrict__ bs, const float* __restrict__ rw, const float* __restrict__ gf,
    const float* __restrict__ bn_g, const float* __restrict__ bn_b,
    const float* __restrict__ gn_g, const float* __restrict__ gn_b,
    float* __restrict__ fused) {
  __shared__ float sh[8];
  __shared__ float wsh[64];
  int b = blockIdx.x, t = threadIdx.x;
  if (t < 64) wsh[t] = rw[b * 64 + t];
  __syncthreads();
  float v0 = 0, v1 = 0, v2 = 0;
  const float* bsb = bs + (size_t)b * 64 * 768;
  for (int k = 0; k < 64; k++) {
    float w = wsh[k];
    if (w != 0.0f) {
      v0 = fmaf(w, bsb[(size_t)k * 768 + t], v0);
      v1 = fmaf(w, bsb[(size_t)k * 768 + t + 256], v1);
      v2 = fmaf(w, bsb[(size_t)k * 768 + t + 512], v2);
    }
  }
  float sx = blockReduceSum(v0 + v1 + v2, sh);
  float sxx = blockReduceSum(v0 * v0 + v1 * v1 + v2 * v2, sh);
  float mean = sx * (1.0f / 768.0f);
  float var = fmaxf(sxx * (1.0f / 768.0f) - mean * mean, 0.0f);
  float rs = rsqrtf(var + 1e-5f);
  float* fb = fused + (size_t)b * 1536;
  fb[768 + t] = (v0 - mean) * rs * bn_g[t] + bn_b[t];
  fb[768 + t + 256] = (v1 - mean) * rs * bn_g[t + 256] + bn_b[t + 256];
  fb[768 + t + 512] = (v2 - mean) * rs * bn_g[t + 512] + bn_b[t + 512];
  const float* gr = gf + (size_t)b * 768;
  float g0 = gr[t], g1 = gr[t + 256], g2 = gr[t + 512];
  float gsx = blockReduceSum(g0 + g1 + g2, sh);
  float gsxx = blockReduceSum(g0 * g0 + g1 * g1 + g2 * g2, sh);
  float gm = gsx * (1.0f / 768.0f);
  float gv = fmaxf(gsxx * (1.0f / 768.0f) - gm * gm, 0.0f);
  float grs = rsqrtf(gv + 1e-5f);
  fb[t] = (g0 - gm) * grs * gn_g[t] + gn_b[t];
  fb[t + 256] = (g1 - gm) * grs * gn_g[t + 256] + gn_b[t + 256];
  fb[t + 512] = (g2 - gm) * grs * gn_g[t + 512] + gn_b[t + 512];
}

// ---------------- K14: h = gelu(fused @ hw1 + hb1) ----------------
__global__ void __launch_bounds__(256) k_head1(
    const float* __restrict__ fused, const float* __restrict__ hw1, const float* __restrict__ hb1,
    float* __restrict__ h) {
  __shared__ float fl[1536];
  int b = blockIdx.y, h0 = blockIdx.x * 256, t = threadIdx.x;
  for (int i = t; i < 1536; i += 256) fl[i] = fused[(size_t)b * 1536 + i];
  __syncthreads();
  int hh = h0 + t;
  float acc = hb1[hh];
  for (int d = 0; d < 1536; d++) acc = fmaf(fl[d], hw1[(size_t)d * 3072 + hh], acc);
  h[(size_t)b * 3072 + hh] = gelu_exact(acc);
}

// ---------------- K15: residual = h @ hw2 + hb2; final = base + residual --------
__global__ void __launch_bounds__(256) k_head2(
    const float* __restrict__ h, const float* __restrict__ hw2, const float* __restrict__ hb2,
    const float* __restrict__ base, float* __restrict__ out) {
  __shared__ float hl[3072];
  int b = blockIdx.y, c0 = blockIdx.x * 256, t = threadIdx.x;
  for (int i = t; i < 3072; i += 256) hl[i] = h[(size_t)b * 3072 + i];
  __syncthreads();
  int c = c0 + t;
  if (c < 1000) {
    float acc = hb2[c];
    for (int k = 0; k < 3072; k++) acc = fmaf(hl[k], hw2[(size_t)k * 1000 + c], acc);
    out[32000 + b * 1000 + c] = acc;
    out[b * 1000 + c] = base[b * 1000 + c] + acc;
  }
}

// ---------------- K16: sparse_loss + diversity_loss ----------------
__global__ void __launch_bounds__(256) k_losses(
    const float* __restrict__ scores, const float* __restrict__ gpart, float* __restrict__ out) {
  __shared__ float sh[8];
  int t = threadIdx.x;
  float s = 0.0f;
#pragma unroll
  for (int i = 0; i < 8; i++) s += scores[t + i * 256];
  s = blockReduceSum(s, sh);
  float gsum = (t < 64) ? gpart[t] : 0.0f;
  gsum = blockReduceSum(gsum, sh);
  if (t == 0) {
    out[66048] = s * (1.0f / 2048.0f);
    out[66049] = gsum * (1.0f / 4096.0f);
  }
}

// ---------------- launch ----------------
extern "C" void kernel_launch(void* const* d_in, const int* in_sizes, int n_in,
                              void* d_out, int out_size, void* d_ws, size_t ws_size,
                              hipStream_t stream) {
  const float* patch = (const float*)d_in[0];
  const float* gfeat = (const float*)d_in[1];
  const float* base  = (const float*)d_in[2];
  const float* bq    = (const float*)d_in[3];
  const float* qn_g  = (const float*)d_in[4];
  const float* qn_b  = (const float*)d_in[5];
  const float* tn_g  = (const float*)d_in[6];
  const float* tn_b  = (const float*)d_in[7];
  const float* bn_g  = (const float*)d_in[8];
  const float* bn_b  = (const float*)d_in[9];
  const float* gn_g  = (const float*)d_in[10];
  const float* gn_b  = (const float*)d_in[11];
  const float* rln_g = (const float*)d_in[12];
  const float* rln_b = (const float*)d_in[13];
  const float* rw1   = (const float*)d_in[14];
  const float* rb1   = (const float*)d_in[15];
  const float* rw2   = (const float*)d_in[16];
  const float* rb2   = (const float*)d_in[17];
  const float* hw1   = (const float*)d_in[18];
  const float* hb1   = (const float*)d_in[19];
  const float* hw2   = (const float*)d_in[20];
  const float* hb2   = (const float*)d_in[21];
  float* ws = (float*)d_ws;
  float* out = (float*)d_out;

  // workspace layout (f32 offsets); total 14536896 f32 = 58.1 MB
  float* As     = ws + 0;         // 131072
  float* Bs     = ws + 131072;
  float* Cs     = ws + 262144;
  float* s1     = ws + 393216;    // 64
  float* qb     = ws + 393280;    // 64
  float* gpart  = ws + 393344;    // 64
  float* scores = ws + 393408;    // 2048
  float* rw_ws  = ws + 395456;    // 2048
  float* fused  = ws + 397504;    // 49152
  float* hbuf   = ws + 446656;    // 98304
  float* bqn    = ws + 544960;    // 49152
  float* qg     = ws + 594112;    // 49152
  float* w1T    = ws + 643264;    // 2359296 (3072x768 f32)
  float* bs     = ws + 3002560;   // 1572864
  float* r      = ws + 4575424;   // 1572864
  float* L      = ws + 6148288;   // 8388608 (32*64*4096 f32)
  float* rh     = L;              // 6291456 — reuses L (dead after k_pv_mfma)

  k_token_stats<<<dim3(131072), 256, 0, stream>>>(patch, tn_g, tn_b, As, Bs, Cs);
  k_prep_queries<<<dim3(64), 256, 0, stream>>>(bq, qn_g, qn_b, tn_g, tn_b, qg, s1, qb, bqn);
  k_gram<<<dim3(64), 256, 0, stream>>>(bqn, gpart);
  k_w1t<<<dim3(24, 96), 256, 0, stream>>>(rw1, w1T);
  k_attn_mfma<<<dim3(32, 32), 256, 0, stream>>>(patch, qg, s1, qb, As, Bs, Cs, L);
  k_softmax<<<dim3(2048), 256, 0, stream>>>(L);
  k_zero<<<dim3(1536), 256, 0, stream>>>(bs);
  k_pv_mfma<<<dim3(6, 32, 4), 256, 0, stream>>>(patch, L, bs);
  k_ln768<<<dim3(2048), 256, 0, stream>>>(bs, rln_g, rln_b, r);
  k_rh_mfma<<<dim3(24, 32), 256, 0, stream>>>(r, w1T, rb1, rh);
  k_scores<<<dim3(2048), 256, 0, stream>>>(rh, rw2, rb2, scores);
  k_topk<<<dim3(32), 64, 0, stream>>>(scores, rw_ws, out + 64000);
  k_fused<<<dim3(32), 256, 0, stream>>>(bs, rw_ws, gfeat, bn_g, bn_b, gn_g, gn_b, fused);
  k_head1<<<dim3(12, 32), 256, 0, stream>>>(fused, hw1, hb1, hbuf);
  k_head2<<<dim3(4, 32), 256, 0, stream>>>(hbuf, hw2, hb2, base, out);
  k_losses<<<dim3(1), 256, 0, stream>>>(scores, gpart, out);
}